// Round 4
// baseline (107.469 us; speedup 1.0000x reference)
//
#include <hip/hip_runtime.h>

// CausalDWT: x (32, 4096, 512) f32.
// p = pad(x, 1 leading zero row on L). even[k]=p[2k]=(k==0?0:x[2k-1]),
// odd[k]=p[2k+1]=x[2k]. lo=even+odd, hi=even-odd, each (32,2048,512).
// d_out = [lo flat | hi flat].

#define C4      128          // 512 floats / 4 per float4
#define KHALF   2048         // L/2
#define LFULL   4096
#define TOTAL4  (32 * KHALF * C4)       // 8,388,608 float4 work items
#define OUTOFS  (32 * KHALF * C4)       // hi offset in float4 units

__global__ __launch_bounds__(256) void causal_dwt_kernel(
    const float4* __restrict__ x,
    float4* __restrict__ lo,
    float4* __restrict__ hi)
{
    int idx    = blockIdx.x * blockDim.x + threadIdx.x;
    int stride = gridDim.x * blockDim.x;

    for (int i = idx; i < TOTAL4; i += stride) {
        int c4 = i & (C4 - 1);          // column chunk
        int bk = i >> 7;                // b*KHALF + k
        int k  = bk & (KHALF - 1);
        int b  = bk >> 11;

        int rowO  = 2 * k;                              // odd operand row in x
        int xbase = ((b << 12) + rowO) << 7;            // (b*4096 + rowO)*128

        float4 o = x[xbase + c4];
        float4 e = make_float4(0.f, 0.f, 0.f, 0.f);
        if (k > 0) e = x[xbase - C4 + c4];              // row 2k-1

        float4 l, h;
        l.x = e.x + o.x;  h.x = e.x - o.x;
        l.y = e.y + o.y;  h.y = e.y - o.y;
        l.z = e.z + o.z;  h.z = e.z - o.z;
        l.w = e.w + o.w;  h.w = e.w - o.w;

        lo[i] = l;
        hi[i] = h;
    }
}

extern "C" void kernel_launch(void* const* d_in, const int* in_sizes, int n_in,
                              void* d_out, int out_size, void* d_ws, size_t ws_size,
                              hipStream_t stream) {
    const float4* x = (const float4*)d_in[0];
    float4* lo = (float4*)d_out;
    float4* hi = lo + OUTOFS;

    const int block = 256;
    const int grid  = 2048;   // ~8 blocks/CU on 256 CUs; grid-stride covers rest

    causal_dwt_kernel<<<grid, block, 0, stream>>>(x, lo, hi);
}

// Round 6
// 79.975 us; speedup vs baseline: 1.3438x; 1.3438x over previous
//
#include <hip/hip_runtime.h>

// CausalDWT: x (32, 4096, 512) f32.
// even[k] = (k==0 ? 0 : x[2k-1]), odd[k] = x[2k];  lo = e+o, hi = e-o.
// Outputs each (32, 2048, 512) f32, concatenated flat in d_out.
//
// Pure streaming: 256 MiB read + 256 MiB write, zero reuse. One float4 work
// item per thread (no grid-stride loop) for maximal TLP; nontemporal stores
// since outputs are never re-read. Native clang vector type so the
// nontemporal builtin accepts the pointer (HIP float4 is a class -> rejected).

typedef float f32x4 __attribute__((ext_vector_type(4)));

#define C4      128                      // 512 floats / 4
#define KHALF   2048                     // L/2
#define TOTAL4  (32 * KHALF * C4)        // 8,388,608 float4 work items
#define OUTOFS  (32 * KHALF * C4)        // hi offset in float4 units

__global__ __launch_bounds__(256) void causal_dwt_kernel(
    const f32x4* __restrict__ x,
    f32x4* __restrict__ lo,
    f32x4* __restrict__ hi)
{
    int i  = blockIdx.x * 256 + threadIdx.x;     // grid sized exactly to TOTAL4
    int c4 = i & (C4 - 1);
    int bk = i >> 7;                             // b*KHALF + k
    int k  = bk & (KHALF - 1);
    int b  = bk >> 11;

    int xbase = ((b << 12) + (k << 1)) << 7;     // (b*4096 + 2k) * 128

    f32x4 o = x[xbase + c4];                     // row 2k   (odd operand)
    f32x4 e = (f32x4)(0.f);
    if (k > 0)                                   // wave-uniform branch
        e = x[xbase - C4 + c4];                  // row 2k-1 (even operand)

    f32x4 l = e + o;
    f32x4 h = e - o;

    __builtin_nontemporal_store(l, &lo[i]);
    __builtin_nontemporal_store(h, &hi[i]);
}

extern "C" void kernel_launch(void* const* d_in, const int* in_sizes, int n_in,
                              void* d_out, int out_size, void* d_ws, size_t ws_size,
                              hipStream_t stream) {
    const f32x4* x = (const f32x4*)d_in[0];
    f32x4* lo = (f32x4*)d_out;
    f32x4* hi = lo + OUTOFS;

    const int block = 256;
    const int grid  = TOTAL4 / block;            // 32768 blocks, one item/thread

    causal_dwt_kernel<<<grid, block, 0, stream>>>(x, lo, hi);
}